// Round 1
// baseline (256.883 us; speedup 1.0000x reference)
//
#include <hip/hip_runtime.h>

#define E_EDGES 3200000
#define N_NODES_K 100000
#define DIM_K 32
#define NEG_INF_F (-10000000000.0f)

// monotonic float->uint key for atomicMax on floats (handles negatives)
__device__ __forceinline__ unsigned fkey(float x) {
    unsigned u = __float_as_uint(x);
    return (u & 0x80000000u) ? ~u : (u | 0x80000000u);
}
__device__ __forceinline__ float fkey_inv(unsigned k) {
    return (k & 0x80000000u) ? __uint_as_float(k ^ 0x80000000u) : __uint_as_float(~k);
}

// ---------------------------------------------------------------------------
// K0: single-thread init + input-dtype detection (deterministic each call)
//   flags[0]: edge_index is int64 (1) or int32 (0)
//   flags[1]: selection is int32 words (0), bytes (1), or float32 (2)
// ---------------------------------------------------------------------------
__global__ void k_init(const void* ei_raw, const void* sel_raw,
                       unsigned* maxkey, float* sum, int* flags) {
    if (blockIdx.x != 0 || threadIdx.x != 0) return;
    // edge_index: values < 2^17, so int64 layout has zero high words.
    const unsigned* w = (const unsigned*)ei_raw;
    int i64 = 1;
    for (int i = 1; i <= 16; ++i) {
        if (w[2 * i + 1] != 0u) { i64 = 0; break; }
    }
    flags[0] = i64;
    // selection encoding
    const unsigned* sw = (const unsigned*)sel_raw;
    bool all01 = true, allf = true;
    for (int i = 0; i < 64; ++i) {
        unsigned v = sw[i];
        if (v != 0u && v != 1u) all01 = false;
        if (v != 0u && v != 0x3F800000u) allf = false;
    }
    flags[1] = all01 ? 0 : (allf ? 2 : 1);
    *maxkey = fkey(-3.0e38f);
    *sum = 0.0f;
}

// ---------------------------------------------------------------------------
// KP: node projections  P1[n] = node_reps[n] @ W1[0:32,:],  P2 = @ W1[32:64,:]
// one thread per node; W1 reads are wave-uniform (scalar-cached)
// ---------------------------------------------------------------------------
__global__ __launch_bounds__(256) void k_nodeproj(
    const float* __restrict__ nr, const float* __restrict__ W1,
    float* __restrict__ P1, float* __restrict__ P2) {
    int n = blockIdx.x * 256 + threadIdx.x;
    if (n >= N_NODES_K) return;
    const float4* x4 = (const float4*)(nr + (size_t)n * 32);
    float xr[32];
#pragma unroll
    for (int i = 0; i < 8; ++i) {
        float4 t = x4[i];
        xr[4 * i + 0] = t.x; xr[4 * i + 1] = t.y; xr[4 * i + 2] = t.z; xr[4 * i + 3] = t.w;
    }
    float4* o1 = (float4*)(P1 + (size_t)n * 32);
    float4* o2 = (float4*)(P2 + (size_t)n * 32);
#pragma unroll
    for (int jb = 0; jb < 8; ++jb) {
        float4 a1 = make_float4(0.f, 0.f, 0.f, 0.f);
        float4 a2 = make_float4(0.f, 0.f, 0.f, 0.f);
#pragma unroll
        for (int k = 0; k < 32; ++k) {
            float xv = xr[k];
            const float4 w1 = *(const float4*)(W1 + (size_t)k * 32 + jb * 4);
            const float4 w2 = *(const float4*)(W1 + (size_t)(32 + k) * 32 + jb * 4);
            a1.x = fmaf(xv, w1.x, a1.x); a1.y = fmaf(xv, w1.y, a1.y);
            a1.z = fmaf(xv, w1.z, a1.z); a1.w = fmaf(xv, w1.w, a1.w);
            a2.x = fmaf(xv, w2.x, a2.x); a2.y = fmaf(xv, w2.y, a2.y);
            a2.z = fmaf(xv, w2.z, a2.z); a2.w = fmaf(xv, w2.w, a2.w);
        }
        o1[jb] = a1; o2[jb] = a2;
    }
}

// ---------------------------------------------------------------------------
// KE: per-edge score = elu(P1[s]+P2[d]+er@W1[64:96]+b1) . (g - sg)
// masked -> NEG_INF. Writes scores to out (staging), block-reduced atomicMax.
// E = 3,200,000 = 12500 * 256 exactly (no tail).
// ---------------------------------------------------------------------------
__global__ __launch_bounds__(256) void k_edge(
    const float* __restrict__ er_, const float* __restrict__ W1,
    const float* __restrict__ b1, const float* __restrict__ gr,
    const float* __restrict__ sgr, const void* __restrict__ ei_raw,
    const void* __restrict__ sel_raw, const float* __restrict__ P1,
    const float* __restrict__ P2, float* __restrict__ scores,
    unsigned* __restrict__ maxkey, const int* __restrict__ flags) {
    const int e = blockIdx.x * 256 + threadIdx.x;
    const int fei = flags[0], fsel = flags[1];

    bool sel;
    if (fsel == 0)      sel = ((const int*)sel_raw)[e] != 0;
    else if (fsel == 1) sel = ((const unsigned char*)sel_raw)[e] != 0;
    else                sel = ((const float*)sel_raw)[e] != 0.0f;

    float score = NEG_INF_F;
    if (!sel) {
        int s, d;
        const int* ei = (const int*)ei_raw;
        if (fei) { s = ei[2 * (size_t)e]; d = ei[2 * (size_t)E_EDGES + 2 * (size_t)e]; }
        else     { s = ei[e];             d = ei[E_EDGES + e]; }

        float acc[32];
        const float4* p1 = (const float4*)(P1 + (size_t)s * 32);
        const float4* p2 = (const float4*)(P2 + (size_t)d * 32);
#pragma unroll
        for (int jb = 0; jb < 8; ++jb) {
            float4 a = p1[jb];
            float4 b = p2[jb];
            const float4 bb = *(const float4*)(b1 + jb * 4);
            acc[4 * jb + 0] = a.x + b.x + bb.x;
            acc[4 * jb + 1] = a.y + b.y + bb.y;
            acc[4 * jb + 2] = a.z + b.z + bb.z;
            acc[4 * jb + 3] = a.w + b.w + bb.w;
        }
        float xr[32];
        const float4* e4 = (const float4*)(er_ + (size_t)e * 32);
#pragma unroll
        for (int i = 0; i < 8; ++i) {
            float4 t = e4[i];
            xr[4 * i + 0] = t.x; xr[4 * i + 1] = t.y; xr[4 * i + 2] = t.z; xr[4 * i + 3] = t.w;
        }
#pragma unroll
        for (int k = 0; k < 32; ++k) {
            const float ek = xr[k];
#pragma unroll
            for (int jb = 0; jb < 8; ++jb) {
                const float4 w = *(const float4*)(W1 + (size_t)(64 + k) * 32 + jb * 4);
                acc[4 * jb + 0] = fmaf(ek, w.x, acc[4 * jb + 0]);
                acc[4 * jb + 1] = fmaf(ek, w.y, acc[4 * jb + 1]);
                acc[4 * jb + 2] = fmaf(ek, w.z, acc[4 * jb + 2]);
                acc[4 * jb + 3] = fmaf(ek, w.w, acc[4 * jb + 3]);
            }
        }
        float sc = 0.0f;
#pragma unroll
        for (int j = 0; j < 32; ++j) {
            float z = acc[j];
            float h = z > 0.0f ? z : (expf(z) - 1.0f);
            float g = gr[j] - sgr[j];
            sc = fmaf(h, g, sc);
        }
        score = sc;
    }
    scores[e] = score;

    // block max reduce -> one atomic per block
    float v = score;
#pragma unroll
    for (int off = 32; off > 0; off >>= 1) v = fmaxf(v, __shfl_down(v, off));
    __shared__ float smax[4];
    const int lane = threadIdx.x & 63, wid = threadIdx.x >> 6;
    if (lane == 0) smax[wid] = v;
    __syncthreads();
    if (threadIdx.x == 0) {
        float m = fmaxf(fmaxf(smax[0], smax[1]), fmaxf(smax[2], smax[3]));
        atomicMax(maxkey, fkey(m));
    }
}

// ---------------------------------------------------------------------------
// KS: out = exp((score - max)/T) in-place, block-sum -> atomicAdd
// float4 per thread; E/4 = 800000 = 3125 * 256 exactly.
// ---------------------------------------------------------------------------
__global__ __launch_bounds__(256) void k_exp(
    float* __restrict__ out, const unsigned* __restrict__ maxkey,
    float* __restrict__ sum) {
    const int i = blockIdx.x * 256 + threadIdx.x;
    const float mx = fkey_inv(*maxkey);
    float4* o4 = (float4*)out;
    float4 s = o4[i];
    float4 p;
    p.x = expf((s.x - mx) * 2.0f);
    p.y = expf((s.y - mx) * 2.0f);
    p.z = expf((s.z - mx) * 2.0f);
    p.w = expf((s.w - mx) * 2.0f);
    o4[i] = p;
    float v = p.x + p.y + p.z + p.w;
#pragma unroll
    for (int off = 32; off > 0; off >>= 1) v += __shfl_down(v, off);
    __shared__ float ssum[4];
    const int lane = threadIdx.x & 63, wid = threadIdx.x >> 6;
    if (lane == 0) ssum[wid] = v;
    __syncthreads();
    if (threadIdx.x == 0) atomicAdd(sum, ssum[0] + ssum[1] + ssum[2] + ssum[3]);
}

// ---------------------------------------------------------------------------
// KN: normalize in-place
// ---------------------------------------------------------------------------
__global__ __launch_bounds__(256) void k_norm(
    float* __restrict__ out, const float* __restrict__ sum) {
    const int i = blockIdx.x * 256 + threadIdx.x;
    const float r = 1.0f / *sum;
    float4* o4 = (float4*)out;
    float4 v = o4[i];
    v.x *= r; v.y *= r; v.z *= r; v.w *= r;
    o4[i] = v;
}

extern "C" void kernel_launch(void* const* d_in, const int* in_sizes, int n_in,
                              void* d_out, int out_size, void* d_ws, size_t ws_size,
                              hipStream_t stream) {
    const float* node_reps    = (const float*)d_in[0];
    const float* edge_reps    = (const float*)d_in[1];
    const float* graph_rep    = (const float*)d_in[2];
    const float* subgraph_rep = (const float*)d_in[3];
    const float* W1           = (const float*)d_in[4];
    const float* b1           = (const float*)d_in[5];
    const void*  ei           = d_in[6];
    const void*  selp         = d_in[7];
    float* out = (float*)d_out;

    char* ws = (char*)d_ws;
    float* P1 = (float*)ws;                                       // 12.8 MB
    float* P2 = (float*)(ws + (size_t)N_NODES_K * 32 * 4);        // 12.8 MB
    char* scal = ws + (size_t)2 * N_NODES_K * 32 * 4;
    unsigned* maxkey = (unsigned*)scal;
    float* sum = (float*)(scal + 4);
    int* flags = (int*)(scal + 8);

    k_init<<<1, 1, 0, stream>>>(ei, selp, maxkey, sum, flags);
    k_nodeproj<<<(N_NODES_K + 255) / 256, 256, 0, stream>>>(node_reps, W1, P1, P2);
    k_edge<<<E_EDGES / 256, 256, 0, stream>>>(edge_reps, W1, b1, graph_rep,
                                              subgraph_rep, ei, selp, P1, P2,
                                              out, maxkey, flags);
    k_exp<<<E_EDGES / 4 / 256, 256, 0, stream>>>(out, maxkey, sum);
    k_norm<<<E_EDGES / 4 / 256, 256, 0, stream>>>(out, sum);
}